// Round 5
// baseline (159.258 us; speedup 1.0000x reference)
//
#include <hip/hip_runtime.h>
#include <math.h>

// SoftDTW gamma=1, B=32, T=512. Exp-domain f64 recurrence (exact; see R3/R4):
//   E[i,j] = w_i * (E[i-1,j] + E[i,j-1] + E[i-1,j-1]),  w_i = exp(-(x_i-y_i)^2)
// R5: pipelined row-strip decomposition across the 4 SIMDs of one CU.
//   Block = 4 waves; wave s owns rows 128s+1..128(s+1); lane l owns 2 rows
//   (128s+2l+1, 128s+2l+2) in registers. All waves run a wall-tick loop; wave
//   s computes global anti-diagonal d = t - s*LAG + 2 at tick t (LAG=34).
//   Strip-boundary row values stream through per-boundary LDS rings indexed
//   by d mod 128; barriers only every L=32 ticks. Ring reads are prefetched
//   PF=2 ticks ahead (two alternating registers) to hide LDS latency.
// Index algebra (verified): reader consumes slots written exactly one epoch
//   earlier (writer tick = reader tick - L); same-epoch writer/reader slot
//   runs are disjoint (offset L, ring 4L). Pre-active cells stay 0 by
//   induction; post-active extended cells never reach valid cells.

#define TLEN  512
#define BATCH 32
#define NW    4              // waves (row strips) per block
#define L     32             // epoch length (ticks between barriers)
#define PF    2              // ring-read prefetch depth (ticks)
#define LAG   (L + PF)       // wall-tick lag between adjacent strips = 34
#define RING  128            // ring slots (= 4*L, power of 2)
#define NEP   35             // full epochs; wave 3 reaches d=1024 at tick 1124
#define TAIL  5              // 35*32 + 5 = 1125 ticks total

__global__ __launch_bounds__(NW * 64) void softdtw_kernel(const float* __restrict__ x,
                                                          const float* __restrict__ y,
                                                          float* __restrict__ out) {
    __shared__ double ring[NW - 1][RING];

    const int b   = blockIdx.x;
    const int tid = threadIdx.x;
    const int s   = tid >> 6;        // strip / wave index, 0..3
    const int l   = tid & 63;        // lane

    // zero rings (first epoch barrier makes this visible)
    for (int i = tid; i < (NW - 1) * RING; i += NW * 64)
        ((double*)ring)[i] = 0.0;

    // row weights: lane l of strip s owns rows 128s+2l+1 (k=0), 128s+2l+2 (k=1)
    const int base = 128 * s;
    double w0, w1;
    {
        const float2* x2 = (const float2*)(x + b * TLEN + base);
        const float2* y2 = (const float2*)(y + b * TLEN + base);
        float2 xv = x2[l], yv = y2[l];
        double e0 = (double)xv.x - (double)yv.x;
        double e1 = (double)xv.y - (double)yv.y;
        w0 = exp(-e0 * e0);
        w1 = exp(-e1 * e1);
    }

    double cur0 = 0.0, cur1 = 0.0, prev0 = 0.0, prev1 = 0.0;
    double nb1 = 0.0;                                  // E[strip_top-1, *] diag d-1
    double nb2 = (s == 0 && l == 0) ? 1.0 : 0.0;       // E[0,0] seed
    double rvA = 0.0, rvB = 0.0;                       // prefetch pipeline (PF=2)
    const double lmask = (s == 0 && l == 0) ? 0.0 : 1.0;

    int d = 2 - s * LAG;                               // global diagonal at tick 0

    // One wall tick. A* = diag d-1, B* = diag d-2 on entry; B* <- diag d.
    auto step = [&](double& A0, double& A1, double& B0, double& B1, double& rv) {
        double bot = w1 * (A0 + A1 + B0);              // row 128s+2l+2 (reads old B0)
        double sh  = __shfl_up(bot, 1, 64);
        if (s < NW - 1) {                              // uniform: strip boundary producer
            if (l == 63) ring[s][d & (RING - 1)] = bot;
        }
        B1 = bot;
        B0 = w0 * (nb1 + A0 + nb2);                    // row 128s+2l+1
        nb2 = nb1;
        if (s == 0) {
            nb1 = sh * lmask;                          // row-0 boundary = 0 at lane 0
        } else {
            nb1 = (l == 0) ? rv : sh;                  // rv = ring value read PF ticks ago
            rv  = ring[s - 1][(d + PF) & (RING - 1)];  // prefetch (broadcast read)
        }
        ++d;
    };

    for (int e = 0; e < NEP; ++e) {
        __syncthreads();
        #pragma unroll 4
        for (int u = 0; u < L / 2; ++u) {
            step(cur0, cur1, prev0, prev1, rvA);       // even tick -> prev
            step(prev0, prev1, cur0, cur1, rvB);       // odd tick  -> cur
        }
    }
    __syncthreads();
    // tail: ticks 1120..1124; wave 3 computes d=1024 at tick 1124 (writes prev)
    step(cur0, cur1, prev0, prev1, rvA);
    step(prev0, prev1, cur0, cur1, rvB);
    step(cur0, cur1, prev0, prev1, rvA);
    step(prev0, prev1, cur0, cur1, rvB);
    step(cur0, cur1, prev0, prev1, rvA);

    // E[512,512] = prev1 of lane 63, wave 3
    if (s == NW - 1 && l == 63) {
        float R = (float)(-log(prev1));
        atomicAdd(out, R * (1.0f / BATCH));
    }
}

extern "C" void kernel_launch(void* const* d_in, const int* in_sizes, int n_in,
                              void* d_out, int out_size, void* d_ws, size_t ws_size,
                              hipStream_t stream) {
    const float* x = (const float*)d_in[0];
    const float* y = (const float*)d_in[1];
    float* out = (float*)d_out;

    hipMemsetAsync(out, 0, sizeof(float), stream);     // d_out is poisoned 0xAA
    softdtw_kernel<<<BATCH, NW * 64, 0, stream>>>(x, y, out);
}

// Round 6
// 131.826 us; speedup vs baseline: 1.2081x; 1.2081x over previous
//
#include <hip/hip_runtime.h>
#include <math.h>

// SoftDTW gamma=1, B=32, T=512. Exp-domain f64 recurrence (exact; R3/R4):
//   E[i,j] = w_i * (E[i-1,j] + E[i,j-1] + E[i-1,j-1]),  w_i = exp(-(x_i-y_i)^2)
// R6: TWO pipelined row strips (2 waves) per batch. Wave s owns rows
// 256s+1..256s+256; lane l owns 4 rows (256s+4l+1..+4) in registers. Wave s
// computes diag = tick + 2 - s*LAG (LAG=24). Strip boundary (row 256) streams
// through a 64-slot LDS ring indexed by diag mod 64.
//   - ring READS are batched: 8 broadcast ds_read_b64 per 8-tick group,
//     double-buffered one full group ahead (~500 cyc slack -> no lgkm stall).
//   - ring WRITES: one predicated ds_write_b64 per tick (fire-and-forget).
//   - __syncthreads every 16 ticks. Visibility: reads at group start tg cover
//     slots tg-14..tg-7; newest was written at tick tg-9, i.e. before the
//     barrier at tg-8 (worst case) -> LAG=24 is exactly sufficient.
//   - consumption slot at tick t is (t+2-LAG); ticks with diag<2 read
//     never-written (zeroed) slots and correctly compute zeros; reuse distance
//     (64 diags) >> read window -> no aliasing.
// Result: wave 1, lane 63, row 512 reaches diag 1024 at tick 1046.

#define TLEN  512
#define BATCH 32
#define LAG   24
#define RING  64
#define NEP   65      // 65 epochs * 16 ticks = 1040, + 7-tick tail = 1047

__global__ __launch_bounds__(128) void softdtw_kernel(const float* __restrict__ x,
                                                      const float* __restrict__ y,
                                                      float* __restrict__ out) {
    __shared__ double ring[RING];

    const int b   = blockIdx.x;
    const int tid = threadIdx.x;
    const int s   = tid >> 6;        // strip/wave: 0 = rows 1..256, 1 = rows 257..512
    const int l   = tid & 63;
    const bool lane0  = (l == 0);
    const bool lane63 = (l == 63);

    if (tid < RING) ring[tid] = 0.0;

    // lane l of strip s owns rows 256s+4l+1..+4 (cost indices 256s+4l..+3)
    const float4* x4 = (const float4*)(x + b * TLEN + 256 * s);
    const float4* y4 = (const float4*)(y + b * TLEN + 256 * s);
    float4 xv = x4[l], yv = y4[l];
    double e0 = (double)xv.x - (double)yv.x;
    double e1 = (double)xv.y - (double)yv.y;
    double e2 = (double)xv.z - (double)yv.z;
    double e3 = (double)xv.w - (double)yv.w;
    const double w0 = exp(-e0 * e0), w1 = exp(-e1 * e1);
    const double w2 = exp(-e2 * e2), w3 = exp(-e3 * e3);

    double P0 = 0, P1 = 0, P2 = 0, P3 = 0;   // diag d-2 buffer (then <- d)
    double C0 = 0, C1 = 0, C2 = 0, C3 = 0;   // diag d-1 buffer
    double nb1 = 0.0;                         // E[strip_top-1, diag-1]
    double nb2 = (s == 0 && lane0) ? 1.0 : 0.0;  // E[0,0] seed
    double rA[8], rB[8];
    #pragma unroll
    for (int u = 0; u < 8; ++u) { rA[u] = 0.0; rB[u] = 0.0; }

    __syncthreads();   // ring zeros visible

    int tg = 0;        // group-start tick

    // One tick. A=diag d-1, B=diag d-2 on entry; B <- diag d. rv = ring slot
    // (t+2-LAG), becomes nb1 for the next tick (wave 1, lane 0 only).
    auto dostep = [&](double& A0, double& A1, double& A2, double& A3,
                      double& B0, double& B1, double& B2, double& B3,
                      double rv, int t) {
        double bot = w3 * (A2 + A3 + B2);                 // strip bottom row
        double sh  = __shfl_up(bot, 1, 64);
        if (s == 0) {
            if (lane63) ring[(t + 2) & (RING - 1)] = bot; // diag = t+2
        }
        B3 = bot;
        B2 = w2 * (A1 + A2 + B1);
        B1 = w1 * (A0 + A1 + B0);
        B0 = w0 * (nb1 + A0 + nb2);                       // strip top row
        nb2 = nb1;
        nb1 = (s == 0) ? (lane0 ? 0.0 : sh)               // row-0 boundary = 0
                       : (lane0 ? rv  : sh);              // ring feed at lane 0
    };

    for (int e = 0; e < NEP; ++e) {
        __syncthreads();
        // group A: consume rA (slots tg-22..tg-15), prefetch rB for next group
        if (s == 1) {
            #pragma unroll
            for (int u = 0; u < 8; ++u) rB[u] = ring[(tg - 14 + u) & (RING - 1)];
        }
        #pragma unroll
        for (int u = 0; u < 8; u += 2) {
            dostep(C0, C1, C2, C3, P0, P1, P2, P3, rA[u],     tg + u);
            dostep(P0, P1, P2, P3, C0, C1, C2, C3, rA[u + 1], tg + u + 1);
        }
        tg += 8;
        // group B: consume rB, prefetch rA
        if (s == 1) {
            #pragma unroll
            for (int u = 0; u < 8; ++u) rA[u] = ring[(tg - 14 + u) & (RING - 1)];
        }
        #pragma unroll
        for (int u = 0; u < 8; u += 2) {
            dostep(C0, C1, C2, C3, P0, P1, P2, P3, rB[u],     tg + u);
            dostep(P0, P1, P2, P3, C0, C1, C2, C3, rB[u + 1], tg + u + 1);
        }
        tg += 8;
    }
    // tail: ticks 1040..1046 (consume rA, loaded at tg=1032 covering 1018..1025)
    dostep(C0, C1, C2, C3, P0, P1, P2, P3, rA[0], tg + 0);
    dostep(P0, P1, P2, P3, C0, C1, C2, C3, rA[1], tg + 1);
    dostep(C0, C1, C2, C3, P0, P1, P2, P3, rA[2], tg + 2);
    dostep(P0, P1, P2, P3, C0, C1, C2, C3, rA[3], tg + 3);
    dostep(C0, C1, C2, C3, P0, P1, P2, P3, rA[4], tg + 4);
    dostep(P0, P1, P2, P3, C0, C1, C2, C3, rA[5], tg + 5);
    dostep(C0, C1, C2, C3, P0, P1, P2, P3, rA[6], tg + 6);  // tick 1046: diag 1024 -> P

    // E[512,512] = P3 of lane 63, wave 1
    if (s == 1 && lane63) {
        float R = (float)(-log(P3));
        atomicAdd(out, R * (1.0f / BATCH));
    }
}

extern "C" void kernel_launch(void* const* d_in, const int* in_sizes, int n_in,
                              void* d_out, int out_size, void* d_ws, size_t ws_size,
                              hipStream_t stream) {
    const float* x = (const float*)d_in[0];
    const float* y = (const float*)d_in[1];
    float* out = (float*)d_out;

    hipMemsetAsync(out, 0, sizeof(float), stream);   // d_out is poisoned 0xAA
    softdtw_kernel<<<BATCH, 128, 0, stream>>>(x, y, out);
}

// Round 8
// 120.082 us; speedup vs baseline: 1.3262x; 1.0978x over previous
//
#include <hip/hip_runtime.h>
#include <math.h>

// SoftDTW gamma=1, B=32, T=512. Exp-domain f64 recurrence (exact; see R3/R4):
//   E[i,j] = w_i * (E[i-1,j] + E[i,j-1] + E[i-1,j-1]),  w_i = exp(-(x_i-y_i)^2)
// R8 = R7 with the DPP direction FIXED: wave_shr1 (ctrl 0x138), not wave_shl1
// (0x130). GCN DPP names follow register bit order: shift RIGHT = lane n gets
// lane n-1 (shuffle-up; cf. AMD's row_shr prefix-scan idiom). R7's shl sent
// the boundary the wrong way -> zero inflow -> E=0 -> -log(0)=inf.
//   - wave_shr1 with bound_ctrl=1 zero-fills lane 0 == row-0 boundary
//     (E[0,j>=1]=0): no mask, no cndmask.
//   - boundary regs (nbA,nbB) role-swap into the dead slot each tick.
//   - B written back-to-front so old B[k-1] (diag d-2) is read before clobber.
// Steady-state tick = 24 f64 VALU + 2 dpp movs, zero memory ops, zero waits.
// Masking-free correctness: pre-active cells stay 0 by induction (only seed is
// lane0 nbB=1 = E[0,0] at d=2); post-active extended cells (j>512) are read
// only by other extended cells and never reach the (512,512) readout.

#define TLEN  512
#define BATCH 32
#define RPL   8      // rows per lane (512 / 64)

// lane l <- lane l-1 (lane 0 <- 0.0), pure VALU via DPP wave_shr1 (0x138).
__device__ __forceinline__ double dpp_shr1_zero(double v) {
    int lo = __builtin_amdgcn_mov_dpp(__double2loint(v), 0x138, 0xF, 0xF, true);
    int hi = __builtin_amdgcn_mov_dpp(__double2hiint(v), 0x138, 0xF, 0xF, true);
    return __hiloint2double(hi, lo);
}

__global__ __launch_bounds__(64) void softdtw_kernel(const float* __restrict__ x,
                                                     const float* __restrict__ y,
                                                     float* __restrict__ out) {
    const int b = blockIdx.x;
    const int l = threadIdx.x;           // 0..63

    double w[RPL];
    #pragma unroll
    for (int k = 0; k < RPL; ++k) {
        double dx = (double)x[b * TLEN + RPL * l + k] - (double)y[b * TLEN + RPL * l + k];
        w[k] = exp(-dx * dx);
    }

    double cur[RPL], prev[RPL];          // cur = diag d-1, prev = diag d-2
    #pragma unroll
    for (int k = 0; k < RPL; ++k) { cur[k] = 0.0; prev[k] = 0.0; }
    double nbA = 0.0;                    // E[8l, *] on diag d-1
    double nbB = (l == 0) ? 1.0 : 0.0;   // E[8l, *] on diag d-2; lane0 = E[0,0] seed

    // One tick: A = diag d-1, B = diag d-2 on entry; B <- diag d.
    // nb1 = E[8l] on diag d-1, nb2 = E[8l] on diag d-2; nb2 <- E[8l] on diag d.
    auto step = [&](double (&A)[RPL], double (&B)[RPL], double& nb1, double& nb2) {
        B[RPL - 1] = w[RPL - 1] * (A[RPL - 2] + A[RPL - 1] + B[RPL - 2]);
        double sh = dpp_shr1_zero(B[RPL - 1]);
        #pragma unroll
        for (int k = RPL - 2; k >= 1; --k)
            B[k] = w[k] * (A[k - 1] + A[k] + B[k - 1]);   // reads old B[k-1] (desc order)
        B[0] = w[0] * (nb1 + A[0] + nb2);
        nb2 = sh;    // dead slot -> becomes nb1 for the next tick via arg swap
    };

    // d = 2 (writes prev), then 511 pairs covering d = 3..1024 (even d -> prev).
    step(cur, prev, nbA, nbB);
    for (int it = 0; it < TLEN - 1; ++it) {
        step(prev, cur, nbB, nbA);       // odd d  -> cur
        step(cur, prev, nbA, nbB);       // even d -> prev
    }

    // E[512,512] = prev[7] of lane 63.
    if (l == 63) {
        float R = (float)(-log(prev[RPL - 1]));
        atomicAdd(out, R * (1.0f / BATCH));
    }
}

extern "C" void kernel_launch(void* const* d_in, const int* in_sizes, int n_in,
                              void* d_out, int out_size, void* d_ws, size_t ws_size,
                              hipStream_t stream) {
    const float* x = (const float*)d_in[0];
    const float* y = (const float*)d_in[1];
    float* out = (float*)d_out;

    hipMemsetAsync(out, 0, sizeof(float), stream);   // d_out is poisoned 0xAA
    softdtw_kernel<<<BATCH, 64, 0, stream>>>(x, y, out);
}

// Round 9
// 97.988 us; speedup vs baseline: 1.6253x; 1.2255x over previous
//
#include <hip/hip_runtime.h>
#include <math.h>

// SoftDTW gamma=1, B=32, T=512, cost d[b][i]=(x_i-y_i)^2 (row-only).
// R9: row-weight-factored exp-domain recurrence, 2 f64 ops/cell (was 3).
//   E[i,j] = w_i*(E[i-1,j] + E[i,j-1] + E[i-1,j-1]),  w_i = exp(-d_i)
//   U = E / prod_{k<=i} w_k  =>  U[i,j] = (U[i-1,j] + U[i-1,j-1]) + w_i*U[i,j-1]
//   (one v_add_f64 + one v_fma_f64). Readout: R = sum(d) - log U - S*ln2.
// Range: U_true(512,512) = e^{sum(d)-R} ~ e^620, so seed U[0,0] = 2^-256
//   recenters (stored max ~ e^440; f64 max e^709; margin > e^170 each way).
//   Flushed-to-zero tiny cells contribute < e^-500 relative — harmless.
// Structure = R8: single wave/batch, lane l owns rows 8l+1..8l+8, 1023
//   anti-diagonal ticks, boundary via DPP wave_shr1 (0x138, lane0 zero-fill =
//   row-0 boundary), dead-slot role swap for diagonal buffers and nb regs.
//   Zero LDS, zero s_waitcnt in the body.

#define TLEN  512
#define BATCH 32
#define RPL   8      // rows per lane (512 / 64)

// lane l <- lane l-1 (lane 0 <- 0.0), pure VALU via DPP wave_shr1 (0x138).
__device__ __forceinline__ double dpp_shr1_zero(double v) {
    int lo = __builtin_amdgcn_mov_dpp(__double2loint(v), 0x138, 0xF, 0xF, true);
    int hi = __builtin_amdgcn_mov_dpp(__double2hiint(v), 0x138, 0xF, 0xF, true);
    return __hiloint2double(hi, lo);
}

__global__ __launch_bounds__(64) void softdtw_kernel(const float* __restrict__ x,
                                                     const float* __restrict__ y,
                                                     float* __restrict__ out) {
    const int b = blockIdx.x;
    const int l = threadIdx.x;           // 0..63
    const double SEED = __hiloint2double(0x2FF00000, 0);   // 2^-256

    double w[RPL];
    double dsum = 0.0;
    #pragma unroll
    for (int k = 0; k < RPL; ++k) {
        double dx = (double)x[b * TLEN + RPL * l + k] - (double)y[b * TLEN + RPL * l + k];
        double c = dx * dx;
        dsum += c;
        w[k] = exp(-c);
    }
    // wave-sum of all 512 row costs (outside hot loop; lane 63's copy used)
    #pragma unroll
    for (int m = 1; m < 64; m <<= 1) dsum += __shfl_xor(dsum, m, 64);

    double cur[RPL], prev[RPL];          // cur = diag d-1, prev = diag d-2
    #pragma unroll
    for (int k = 0; k < RPL; ++k) { cur[k] = 0.0; prev[k] = 0.0; }
    double nbA = 0.0;                    // U[8l, diag d-1]
    double nbB = (l == 0) ? SEED : 0.0;  // U[8l, diag d-2]; lane0 = U[0,0] seed

    // One tick: A = diag d-1, B = diag d-2 on entry; B <- diag d.
    // U_new[k] = (up + diag) + w*left = (A[k-1] + B[k-1]) + w[k]*A[k].
    auto step = [&](double (&A)[RPL], double (&B)[RPL], double& nb1, double& nb2) {
        B[RPL - 1] = (A[RPL - 2] + B[RPL - 2]) + w[RPL - 1] * A[RPL - 1];
        double sh = dpp_shr1_zero(B[RPL - 1]);
        #pragma unroll
        for (int k = RPL - 2; k >= 1; --k)
            B[k] = (A[k - 1] + B[k - 1]) + w[k] * A[k];   // old B[k-1] (desc order)
        B[0] = (nb1 + nb2) + w[0] * A[0];
        nb2 = sh;    // dead slot -> becomes nb1 next tick via arg swap
    };

    // d = 2 (writes prev), then 511 pairs covering d = 3..1024 (even d -> prev).
    step(cur, prev, nbA, nbB);
    for (int it = 0; it < TLEN - 1; ++it) {
        step(prev, cur, nbB, nbA);       // odd d  -> cur
        step(cur, prev, nbA, nbB);       // even d -> prev
    }

    // U_stored[512,512] = prev[7] of lane 63.
    // R = sum(d) - log(U_true) = dsum - log(U_stored) - 256*ln2.
    if (l == 63) {
        float R = (float)(dsum - log(prev[RPL - 1]) - 177.445678223345993274);
        atomicAdd(out, R * (1.0f / BATCH));
    }
}

extern "C" void kernel_launch(void* const* d_in, const int* in_sizes, int n_in,
                              void* d_out, int out_size, void* d_ws, size_t ws_size,
                              hipStream_t stream) {
    const float* x = (const float*)d_in[0];
    const float* y = (const float*)d_in[1];
    float* out = (float*)d_out;

    hipMemsetAsync(out, 0, sizeof(float), stream);   // d_out is poisoned 0xAA
    softdtw_kernel<<<BATCH, 64, 0, stream>>>(x, y, out);
}